// Round 17
// baseline (64.453 us; speedup 1.0000x reference)
//
#include <hip/hip_runtime.h>
#include <hip/hip_bf16.h>
#include <math.h>

// SDGCN fused, v17 = v16 (software-pipelined QK one step ahead) + the
// missing POST-LOOP BARRIER. v16's race: loop body begins (not ends) with
// __syncthreads(), so after the final iteration the merge writes to Har
// (LB+1792..19200, which OVERLAPS Vb0 @18432) ran concurrently with other
// waves' PV(15) reads of Vb0 (tile 15 = buffer 15%3 = Vb0). One barrier
// after the loop restores v15's ordering.
//
// Pipeline (verified ordering, 1 barrier/step):
//   window ts: QK reads k_rd(tile ts+1) | PV reads v_rd(tile ts) |
//              stK writes k_wr(buf of tile ts) | stV writes v_w2(buf of ts-1)
//   all read/write pairs land in different windows or different buffers.
//
// mfma_f32_32x32x16_bf16 layouts (m74/m101-verified C/D; standard A/B):
//   A-frag: lane l holds A[l&31][(l>>5)*8+e]
//   B-frag: lane l holds B[(l>>5)*8+e][l&31]
//   C/D:    lane l, reg r holds C[(r&3)+8*(r>>2)+4*(l>>5)][l&31]

typedef short bf16x8 __attribute__((ext_vector_type(8)));
typedef float f32x4  __attribute__((ext_vector_type(4)));
typedef float f32x16 __attribute__((ext_vector_type(16)));
typedef int   i32x4  __attribute__((ext_vector_type(4)));

constexpr int kN = 1024;
constexpr int kD = 64;
constexpr size_t kPlane    = 48u * 1024u * 64u;      // shorts per bf16 plane
constexpr size_t kAfShorts = 16u * 32u * 2048u;      // prearranged A (bf16)
constexpr float  kLog2e    = 1.4426950408889634f;

#define MFMA32(a,b,c) __builtin_amdgcn_mfma_f32_32x32x16_bf16((a),(b),(c),0,0,0)
#define MFMA16(a,b,c) __builtin_amdgcn_mfma_f32_16x16x32_bf16((a),(b),(c),0,0,0)

__device__ __forceinline__ void splitv(float v, short& h, short& l) {
  unsigned u = __float_as_uint(v);
  h = (short)(u >> 16);
  float hf = __uint_as_float(u & 0xFFFF0000u);
  l = (short)(__float_as_uint(v - hf) >> 16);
}

// round-to-nearest-even bf16
__device__ __forceinline__ short rndbf(float v) {
  unsigned u = __float_as_uint(v);
  return (short)((u + 0x7FFFu + ((u >> 16) & 1u)) >> 16);
}

// pack two floats to bf16 pair (truncation)
__device__ __forceinline__ unsigned pkbf(float a, float b) {
  return (__float_as_uint(a) >> 16) | (__float_as_uint(b) & 0xFFFF0000u);
}

// ---------------- pre-pass 1 (v15-verified): X -> RNE bf16 + transpose ----
__global__ __launch_bounds__(256)
void presplit(const float* __restrict__ X, short* __restrict__ Xh,
              short* __restrict__ XTh)
{
  __shared__ short Sh[64][68];
  const int t  = threadIdx.x;
  const int bt = blockIdx.x >> 4;
  const int mb = blockIdx.x & 15;
  const size_t base = (size_t)bt * 65536 + (size_t)mb * 64 * 64;

#pragma unroll
  for (int k = 0; k < 4; ++k) {
    int idx = t + k * 256;
    int row = idx >> 4;
    int c4  = (idx & 15) * 4;
    float4 v = *(const float4*)(X + base + row * 64 + c4);
    short4 hv = make_short4(rndbf(v.x), rndbf(v.y), rndbf(v.z), rndbf(v.w));
    *(short4*)(Xh + base + row * 64 + c4) = hv;
    *(short4*)&Sh[row][c4] = hv;
  }
  __syncthreads();

  const size_t tbase = (size_t)bt * 65536 + (size_t)mb * 64;
#pragma unroll
  for (int k = 0; k < 2; ++k) {
    int idx = t + k * 256;
    int d   = idx >> 3;
    int m8  = (idx & 7) * 8;
    bf16x8 hv;
#pragma unroll
    for (int j = 0; j < 8; ++j) hv[j] = Sh[m8 + j][d];
    *(bf16x8*)(XTh + tbase + (size_t)d * 1024 + m8) = hv;
  }
}

// ---------------- pre-pass 2 (v9-verified): A -> bf16 fragment order ------
__global__ __launch_bounds__(256)
void prearr_Abf(const float* __restrict__ A, short* __restrict__ Af)
{
  const int qt  = blockIdx.x >> 5;
  const int gks = blockIdx.x & 31;
  const int kb  = gks * 32;
  const int s   = threadIdx.x;
  short* dst = Af + ((size_t)(qt * 32 + gks) * 2048);

  const int qw = s >> 7;
  const int ln = (s >> 1) & 63;
  const int p  = s & 1;
  const int q  = qt * 64 + qw * 32 + (ln & 31);
  const int h  = ln >> 5;
  const int k0 = kb + 16 * p + 4 * h;
  float4 f0 = *(const float4*)(A + (size_t)q * kN + k0);
  float4 f1 = *(const float4*)(A + (size_t)q * kN + k0 + 8);
  i32x4 u;
  u[0] = (int)pkbf(f0.x, f0.y); u[1] = (int)pkbf(f0.z, f0.w);
  u[2] = (int)pkbf(f1.x, f1.y); u[3] = (int)pkbf(f1.z, f1.w);
  *(i32x4*)(dst + (size_t)qw * 1024 + ln * 16 + p * 8) = u;
}

// ---------------- main fused kernel ----------------
template<int AMODE>
__global__ __launch_bounds__(256)
void sdgcn_v17(const float* __restrict__ X, const float* __restrict__ A,
               const float* __restrict__ W, const float* __restrict__ gamma,
               const float* __restrict__ beta, float* __restrict__ out,
               const short* __restrict__ Xh, const short* __restrict__ XTh,
               const short* __restrict__ Af)
{
  // LDS 49152B: K 2 bufs x 2kg x 4608B @0; V 3 bufs x 2kg x 5120B @18432.
  // post-loop union (AFTER the post-loop barrier): aM/aZ/aF @0, Har @1792.
  __shared__ __align__(16) unsigned char LB[49152];

  const int t    = threadIdx.x;
  const int wave = t >> 6;
  const int lane = t & 63;
  const int kg   = wave >> 1;
  const int qw   = wave & 1;
  const int half = lane >> 5;
  const int l31  = lane & 31;
  const int bid  = blockIdx.x;
  const int swz  = (bid & 7) * 96 + (bid >> 3);   // XCD-chunked (768 = 8*96)
  const int bt   = swz >> 4;
  const int qt   = swz & 15;
  const int qblk = qt * 64;
  const size_t xb = (size_t)bt * 65536;

  short* Kb0 = (short*)(LB + kg * 4608);
  short* Kb1 = (short*)(LB + 9216 + kg * 4608);
  short* Vb0 = (short*)(LB + 18432 + kg * 5120);
  short* Vb1 = (short*)(LB + 28672 + kg * 5120);
  short* Vb2 = (short*)(LB + 38912 + kg * 5120);
  float* aM  = (float*)LB;             // [2][64]
  float* aZ  = aM + 128;
  float* aF  = aZ + 128;               // [3][64]
  float* Har = (float*)(LB + 1792);    // [64][68]

  // ---- Q B-frags (RNE bf16, hi only)
  const int qmine = qblk + qw * 32 + l31;
  bf16x8 qh[4];
#pragma unroll
  for (int c = 0; c < 4; ++c)
    qh[c] = *(const bf16x8*)(Xh + xb + (size_t)qmine * kD + 16 * c + half * 8);

  f32x16 o0, o1;
#pragma unroll
  for (int r = 0; r < 16; ++r) { o0[r] = 0.f; o1[r] = 0.f; }
  float mrun = -INFINITY, Z = 0.f;

  const int tg = t & 127;

  auto ldK = [&](int kb, int j, bf16x8& h) {
    int ck = tg + 128 * j; int kr = ck >> 3; int kc = (ck & 7) * 8;
    h = *(const bf16x8*)(Xh + xb + (size_t)(kb + kr) * kD + kc);
  };
  auto ldV = [&](int kb, int j, bf16x8& h) {
    int cv = tg + 128 * j; int vd = cv >> 2; int vm = (cv & 3) * 8;
    h = *(const bf16x8*)(XTh + xb + (size_t)vd * 1024 + kb + vm);
  };
  auto stK = [&](short* Kh, int j, bf16x8 h) {
    int ck = tg + 128 * j; int kr = ck >> 3; int kc = (ck & 7) * 8;
    *(bf16x8*)&Kh[kr * 72 + kc] = h;
  };
  auto stV = [&](short* Vt, int j, bf16x8 h) {
    int cv = tg + 128 * j; int vd = cv >> 2; int vm = (cv & 3) * 8;
    *(bf16x8*)&Vt[vd * 40 + vm] = h;
  };

  // issue QK for one tile
  auto QK = [&](const short* Khg, f32x16& sa) {
#pragma unroll
    for (int r = 0; r < 16; ++r) sa[r] = 0.f;
    __builtin_amdgcn_s_setprio(1);
#pragma unroll
    for (int c = 0; c < 4; ++c) {
      bf16x8 kh = *(const bf16x8*)&Khg[l31 * 72 + 16 * c + half * 8];
      sa = MFMA32(kh, qh[c], sa);
    }
    __builtin_amdgcn_s_setprio(0);
  };

  i32x4 aA = {0,0,0,0}, aB = {0,0,0,0};

  // ---- prologue: stage tile0 -> buf0; A(step0); QK(0); stage tile1 ----
  {
    bf16x8 a0,b0,c0,d0;
    ldK(kg * 512, 0, a0); ldK(kg * 512, 1, b0);
    ldV(kg * 512, 0, c0); ldV(kg * 512, 1, d0);
    stK(Kb0, 0, a0); stK(Kb0, 1, b0); stV(Vb0, 0, c0); stV(Vb0, 1, d0);
  }
  if (AMODE == 1) {
    const short* Ab = Af + ((size_t)(qt * 32 + kg * 16) * 2048)
                         + (size_t)qw * 1024 + (lane << 4);
    aA = *(const i32x4*)(Ab);
    aB = *(const i32x4*)(Ab + 8);
  }
  __syncthreads();

  f32x16 sa_prev;
  QK(Kb0, sa_prev);          // tile 0
  {
    bf16x8 a0,b0,c0,d0;      // stage tile 1 (different buffers than tile 0)
    ldK(kg * 512 + 32, 0, a0); ldK(kg * 512 + 32, 1, b0);
    ldV(kg * 512 + 32, 0, c0); ldV(kg * 512 + 32, 1, d0);
    stK(Kb1, 0, a0); stK(Kb1, 1, b0); stV(Vb1, 0, c0); stV(Vb1, 1, d0);
  }

  short* k_rd = Kb1;   // K tile t+1
  short* k_wr = Kb0;   // K tile t+2 destination
  short* v_rd = Vb0;   // V tile t
  short* v_rot = Vb1;  // V tile t+1 (in flight)
  short* v_w2 = Vb2;   // V tile t+2 destination

  for (int ts = 0; ts < 16; ++ts) {
    __syncthreads();   // tile ts+1 staged; prior-buffer readers done

    // ---- issue QK(ts+1) — latency hides under softmax(ts) below
    f32x16 sa_new;
    if (ts < 15) QK(k_rd, sa_new);

    // ---- issue global loads for tile ts+2 and A(ts+1)
    bf16x8 nk0, nk1, nv0, nv1;
    if (ts < 14) {
      const int kb2 = kg * 512 + (ts + 2) * 32;
      ldK(kb2, 0, nk0); ldK(kb2, 1, nk1);
      ldV(kb2, 0, nv0); ldV(kb2, 1, nv1);
    }
    i32x4 naA = {0,0,0,0}, naB = {0,0,0,0};
    if (AMODE == 1 && ts < 15) {
      const short* Ab = Af + ((size_t)(qt * 32 + kg * 16 + ts + 1) * 2048)
                           + (size_t)qw * 1024 + (lane << 4);
      naA = *(const i32x4*)(Ab);
      naB = *(const i32x4*)(Ab + 8);
    }

    // ---- A gate for step ts
    float agv[16];
    if (AMODE == 1) {
      unsigned u[8] = {(unsigned)aA[0],(unsigned)aA[1],(unsigned)aA[2],(unsigned)aA[3],
                       (unsigned)aB[0],(unsigned)aB[1],(unsigned)aB[2],(unsigned)aB[3]};
#pragma unroll
      for (int m = 0; m < 8; ++m) {
        agv[2*m]   = __uint_as_float(u[m] << 16);
        agv[2*m+1] = __uint_as_float(u[m] & 0xFFFF0000u);
      }
    } else {
      const float* Arow = A + (size_t)qmine * kN + kg * 512 + ts * 32 + 4 * half;
      float4 ag0 = *(const float4*)(Arow);
      float4 ag1 = *(const float4*)(Arow + 8);
      float4 ag2 = *(const float4*)(Arow + 16);
      float4 ag3 = *(const float4*)(Arow + 24);
#pragma unroll
      for (int e = 0; e < 4; ++e) {
        agv[e] = ag0[e]; agv[4+e] = ag1[e]; agv[8+e] = ag2[e]; agv[12+e] = ag3[e];
      }
    }

    // ---- softmax(sa_prev) — overlaps QK(ts+1) MFMA latency
    float a0 = fmaxf(fmaxf(sa_prev[0],  sa_prev[1]),  sa_prev[2]);
    float a1 = fmaxf(fmaxf(sa_prev[3],  sa_prev[4]),  sa_prev[5]);
    float a2 = fmaxf(fmaxf(sa_prev[6],  sa_prev[7]),  sa_prev[8]);
    float a3 = fmaxf(fmaxf(sa_prev[9],  sa_prev[10]), sa_prev[11]);
    float a4 = fmaxf(fmaxf(sa_prev[12], sa_prev[13]), sa_prev[14]);
    float b0 = fmaxf(fmaxf(a0, a1), a2);
    float sm = fmaxf(fmaxf(b0, fmaxf(a3, a4)), sa_prev[15]);
    sm = fmaxf(sm, __shfl_xor(sm, 32, 64));
    if (__any(sm > mrun + 8.f)) {
      const float nm = fmaxf(mrun, sm);
      const float f  = exp2f((mrun - nm) * kLog2e);   // 0 on first tile
      mrun = nm; Z *= f;
#pragma unroll
      for (int r = 0; r < 16; ++r) {
        const float fr = __shfl(f, (r & 3) + 8 * (r >> 2) + 4 * half, 64);
        o0[r] *= fr; o1[r] *= fr;
      }
    }
    const float mb2 = mrun * kLog2e;
    float pv[16];
#pragma unroll
    for (int r = 0; r < 16; ++r) pv[r] = exp2f(fmaf(sa_prev[r], kLog2e, -mb2));
    float z0 = (pv[0] + pv[1]) + (pv[2] + pv[3]);
    float z1 = (pv[4] + pv[5]) + (pv[6] + pv[7]);
    float z2 = (pv[8] + pv[9]) + (pv[10] + pv[11]);
    float z3 = (pv[12] + pv[13]) + (pv[14] + pv[15]);
    float zt = (z0 + z1) + (z2 + z3);
    zt += __shfl_xor(zt, 32, 64);
    Z += zt;

    float pa[16];
#pragma unroll
    for (int r = 0; r < 16; ++r) pa[r] = pv[r] * agv[r];

    // ---- pack gated P + 4-shuffle cross-half exchange (v13-verified)
    unsigned du[8];
#pragma unroll
    for (int j = 0; j < 8; ++j) du[j] = pkbf(pa[2*j], pa[2*j+1]);
    const bool lo = (half == 0);
    unsigned snd0 = lo ? du[2] : du[0];
    unsigned snd1 = lo ? du[3] : du[1];
    unsigned snd2 = lo ? du[6] : du[4];
    unsigned snd3 = lo ? du[7] : du[5];
    unsigned r0 = (unsigned)__shfl_xor((int)snd0, 32, 64);
    unsigned r1 = (unsigned)__shfl_xor((int)snd1, 32, 64);
    unsigned r2 = (unsigned)__shfl_xor((int)snd2, 32, 64);
    unsigned r3 = (unsigned)__shfl_xor((int)snd3, 32, 64);
    i32x4 w0, w1;
    w0[0] = (int)(lo ? du[0] : r0);
    w0[1] = (int)(lo ? du[1] : r1);
    w0[2] = (int)(lo ? r0 : du[2]);
    w0[3] = (int)(lo ? r1 : du[3]);
    w1[0] = (int)(lo ? du[4] : r2);
    w1[1] = (int)(lo ? du[5] : r3);
    w1[2] = (int)(lo ? r2 : du[6]);
    w1[3] = (int)(lo ? r3 : du[7]);
    bf16x8 pf0 = *(bf16x8*)&w0;
    bf16x8 pf1 = *(bf16x8*)&w1;

    // ---- PV(ts): O[q][d] += P[q][k] V[k][d]
    {
      bf16x8 v0 = *(const bf16x8*)&v_rd[l31 * 40 + half * 8];
      bf16x8 v1 = *(const bf16x8*)&v_rd[l31 * 40 + 16 + half * 8];
      bf16x8 v2 = *(const bf16x8*)&v_rd[(32 + l31) * 40 + half * 8];
      bf16x8 v3 = *(const bf16x8*)&v_rd[(32 + l31) * 40 + 16 + half * 8];
      __builtin_amdgcn_s_setprio(1);
      o0 = MFMA32(pf0, v0, o0);
      o0 = MFMA32(pf1, v1, o0);
      o1 = MFMA32(pf0, v2, o1);
      o1 = MFMA32(pf1, v3, o1);
      __builtin_amdgcn_s_setprio(0);
    }

    // ---- stage tile ts+2
    if (ts < 14) {
      stK(k_wr, 0, nk0); stK(k_wr, 1, nk1);
      stV(v_w2, 0, nv0); stV(v_w2, 1, nv1);
    }

    // rotate buffers, advance pipeline registers
    { short* tmp = k_rd; k_rd = k_wr; k_wr = tmp; }
    { short* tmp = v_rd; v_rd = v_rot; v_rot = v_w2; v_w2 = tmp; }
    sa_prev = sa_new;
    aA = naA; aB = naB;
  }
  __syncthreads();   // v16 FIX: last PV reads of Vb0 complete before Har
                     // (LB+1792..19200 overlaps Vb0 @18432) is written

  // ================= split-K merge (v5-verified) =================
  if (lane < 32) {
    aM[kg * 64 + qw * 32 + l31] = mrun;
    aZ[kg * 64 + qw * 32 + l31] = Z;
  }
  if (kg == 1) {
#pragma unroll
    for (int r = 0; r < 16; ++r) {
      const int qq = qw * 32 + (r & 3) + 8 * (r >> 2) + 4 * half;
      Har[qq * 68 + l31]      = o0[r];
      Har[qq * 68 + l31 + 32] = o1[r];
    }
  }
  __syncthreads();
  if (kg == 1 && lane < 32) {
    const int q = qw * 32 + l31;
    const float ma = aM[q], mb = mrun;
    const float m  = fmaxf(ma, mb);
    const float fa = __expf(ma - m), fb = __expf(mb - m);
    const float Zs = aZ[q] * fa + Z * fb;
    aF[q]       = fa;
    aF[64 + q]  = fb;
    aF[128 + q] = 1.0f / (8.0f * Zs);   // sqrt(64)=8
  }
  __syncthreads();
  if (kg == 0) {
#pragma unroll
    for (int r = 0; r < 16; ++r) {
      const int qq = qw * 32 + (r & 3) + 8 * (r >> 2) + 4 * half;
      const float fa = aF[qq], fb = aF[64 + qq];
      Har[qq * 68 + l31]      = o0[r] * fa + Har[qq * 68 + l31]      * fb;
      Har[qq * 68 + l31 + 32] = o1[r] * fa + Har[qq * 68 + l31 + 32] * fb;
    }
  }
  __syncthreads();

  // ================= epilogue (v2-verified 16x16 path) =================
  const int g  = lane >> 4;
  const int ql = lane & 15;
  const int er = wave * 16;
  const float i8z = aF[128 + er + ql];

  bf16x8 hh[2], hl[2];
#pragma unroll
  for (int kk = 0; kk < 2; ++kk) {
    const float* hp = &Har[(er + ql) * 68 + kk * 32 + g * 8];
    float4 v0 = *(const float4*)hp;
    float4 v1 = *(const float4*)(hp + 4);
    float v[8] = {v0.x*i8z, v0.y*i8z, v0.z*i8z, v0.w*i8z,
                  v1.x*i8z, v1.y*i8z, v1.z*i8z, v1.w*i8z};
#pragma unroll
    for (int e = 0; e < 8; ++e) { short a, b; splitv(v[e], a, b); hh[kk][e] = a; hl[kk][e] = b; }
  }

  f32x4 lin[4];
#pragma unroll
  for (int c = 0; c < 4; ++c) {
    bf16x8 wh[2], wl[2];
#pragma unroll
    for (int kk = 0; kk < 2; ++kk) {
      const float* wp = W + (size_t)(c * 16 + ql) * kD + kk * 32 + g * 8;
      float4 v0 = *(const float4*)wp;
      float4 v1 = *(const float4*)(wp + 4);
      float v[8] = {v0.x, v0.y, v0.z, v0.w, v1.x, v1.y, v1.z, v1.w};
#pragma unroll
      for (int e = 0; e < 8; ++e) { short a, b; splitv(v[e], a, b); wh[kk][e] = a; wl[kk][e] = b; }
    }
    f32x4 acc = {0.f, 0.f, 0.f, 0.f};
    acc = MFMA16(hh[0], wh[0], acc);
    acc = MFMA16(hh[1], wh[1], acc);
    acc = MFMA16(hh[0], wl[0], acc);
    acc = MFMA16(hh[1], wl[1], acc);
    acc = MFMA16(hl[0], wh[0], acc);
    acc = MFMA16(hl[1], wh[1], acc);
    lin[c] = acc;
  }

  float rl[4][4];
#pragma unroll
  for (int c = 0; c < 4; ++c)
#pragma unroll
    for (int r = 0; r < 4; ++r) rl[c][r] = fmaxf(lin[c][r], 0.f);

  float mu[4], rstd[4];
#pragma unroll
  for (int r = 0; r < 4; ++r) {
    float s1 = rl[0][r] + rl[1][r] + rl[2][r] + rl[3][r];
    float s2 = rl[0][r]*rl[0][r] + rl[1][r]*rl[1][r] + rl[2][r]*rl[2][r] + rl[3][r]*rl[3][r];
#pragma unroll
    for (int off = 1; off < 16; off <<= 1) {
      s1 += __shfl_xor(s1, off, 64);
      s2 += __shfl_xor(s2, off, 64);
    }
    mu[r] = s1 * (1.f / 64.f);
    const float var = s2 * (1.f / 64.f) - mu[r] * mu[r];
    rstd[r] = rsqrtf(var + 1e-5f);
  }

#pragma unroll
  for (int c = 0; c < 4; ++c) {
    const float gm = gamma[c * 16 + ql];
    const float bb = beta[c * 16 + ql];
#pragma unroll
    for (int r = 0; r < 4; ++r) {
      const int qrow = qblk + er + 4 * g + r;
      const size_t off = ((size_t)bt * kN + qrow) * kD + c * 16 + ql;
      out[off] = (rl[c][r] - mu[r]) * rstd[r] * gm + bb + X[off];
    }
  }
}

extern "C" void kernel_launch(void* const* d_in, const int* in_sizes, int n_in,
                              void* d_out, int out_size, void* d_ws, size_t ws_size,
                              hipStream_t stream) {
  const float* X     = (const float*)d_in[0];
  const float* A     = (const float*)d_in[1];
  const float* W     = (const float*)d_in[2];
  const float* gamma = (const float*)d_in[3];
  const float* beta  = (const float*)d_in[4];
  float* out = (float*)d_out;

  short* Xh  = (short*)d_ws;
  short* XTh = Xh  + kPlane;
  short* Af  = XTh + kPlane;

  const size_t need = (2 * kPlane + kAfShorts) * sizeof(short);

  presplit<<<dim3(48 * 16), 256, 0, stream>>>(X, Xh, XTh);
  if (ws_size >= need) {
    prearr_Abf<<<dim3(16 * 32), 256, 0, stream>>>(A, Af);
    sdgcn_v17<1><<<dim3(48 * 16), 256, 0, stream>>>(X, A, W, gamma, beta, out,
                                                    Xh, XTh, Af);
  } else {
    sdgcn_v17<0><<<dim3(48 * 16), 256, 0, stream>>>(X, A, W, gamma, beta, out,
                                                    Xh, XTh, Af);
  }
}

// Round 18
// 63.011 us; speedup vs baseline: 1.0229x; 1.0229x over previous
//
#include <hip/hip_runtime.h>
#include <hip/hip_bf16.h>
#include <math.h>

// SDGCN fused, v18 = v15 (verified 56.7us main) with the k-loop made
// BARRIER-FREE via wave-private single-buffered LDS tiles.
// Correctness basis: LDS ops from one wave are processed IN ORDER
// (lgkmcnt is in-order for DS), so within a wave: PV reads of tile t
// precede the ds_writes of tile t+1 to the same addresses (compiler keeps
// program order for aliasing LDS accesses), and next iteration's QK reads
// queue after those writes. No __syncthreads needed until the merge, which
// overlays the tile region (one post-loop barrier).
// Cost: each wave stages its own tile (2x staging vs kg-shared) — but waves
// fully desynchronize, removing the 4-wave lockstep stall.
//
// mfma_f32_32x32x16_bf16 layouts (m74/m101-verified C/D; standard A/B):
//   A-frag: lane l holds A[l&31][(l>>5)*8+e]
//   B-frag: lane l holds B[(l>>5)*8+e][l&31]
//   C/D:    lane l, reg r holds C[(r&3)+8*(r>>2)+4*(l>>5)][l&31]

typedef short bf16x8 __attribute__((ext_vector_type(8)));
typedef float f32x4  __attribute__((ext_vector_type(4)));
typedef float f32x16 __attribute__((ext_vector_type(16)));
typedef int   i32x4  __attribute__((ext_vector_type(4)));

constexpr int kN = 1024;
constexpr int kD = 64;
constexpr size_t kPlane    = 48u * 1024u * 64u;      // shorts per bf16 plane
constexpr size_t kAfShorts = 16u * 32u * 2048u;      // prearranged A (bf16)
constexpr float  kLog2e    = 1.4426950408889634f;

#define MFMA32(a,b,c) __builtin_amdgcn_mfma_f32_32x32x16_bf16((a),(b),(c),0,0,0)
#define MFMA16(a,b,c) __builtin_amdgcn_mfma_f32_16x16x32_bf16((a),(b),(c),0,0,0)

__device__ __forceinline__ void splitv(float v, short& h, short& l) {
  unsigned u = __float_as_uint(v);
  h = (short)(u >> 16);
  float hf = __uint_as_float(u & 0xFFFF0000u);
  l = (short)(__float_as_uint(v - hf) >> 16);
}

// round-to-nearest-even bf16
__device__ __forceinline__ short rndbf(float v) {
  unsigned u = __float_as_uint(v);
  return (short)((u + 0x7FFFu + ((u >> 16) & 1u)) >> 16);
}

// pack two floats to bf16 pair (truncation)
__device__ __forceinline__ unsigned pkbf(float a, float b) {
  return (__float_as_uint(a) >> 16) | (__float_as_uint(b) & 0xFFFF0000u);
}

// ---------------- pre-pass 1 (v15-verified): X -> RNE bf16 + transpose ----
__global__ __launch_bounds__(256)
void presplit(const float* __restrict__ X, short* __restrict__ Xh,
              short* __restrict__ XTh)
{
  __shared__ short Sh[64][68];
  const int t  = threadIdx.x;
  const int bt = blockIdx.x >> 4;
  const int mb = blockIdx.x & 15;
  const size_t base = (size_t)bt * 65536 + (size_t)mb * 64 * 64;

#pragma unroll
  for (int k = 0; k < 4; ++k) {
    int idx = t + k * 256;
    int row = idx >> 4;
    int c4  = (idx & 15) * 4;
    float4 v = *(const float4*)(X + base + row * 64 + c4);
    short4 hv = make_short4(rndbf(v.x), rndbf(v.y), rndbf(v.z), rndbf(v.w));
    *(short4*)(Xh + base + row * 64 + c4) = hv;
    *(short4*)&Sh[row][c4] = hv;
  }
  __syncthreads();

  const size_t tbase = (size_t)bt * 65536 + (size_t)mb * 64;
#pragma unroll
  for (int k = 0; k < 2; ++k) {
    int idx = t + k * 256;
    int d   = idx >> 3;
    int m8  = (idx & 7) * 8;
    bf16x8 hv;
#pragma unroll
    for (int j = 0; j < 8; ++j) hv[j] = Sh[m8 + j][d];
    *(bf16x8*)(XTh + tbase + (size_t)d * 1024 + m8) = hv;
  }
}

// ---------------- pre-pass 2 (v9-verified): A -> bf16 fragment order ------
__global__ __launch_bounds__(256)
void prearr_Abf(const float* __restrict__ A, short* __restrict__ Af)
{
  const int qt  = blockIdx.x >> 5;
  const int gks = blockIdx.x & 31;
  const int kb  = gks * 32;
  const int s   = threadIdx.x;
  short* dst = Af + ((size_t)(qt * 32 + gks) * 2048);

  const int qw = s >> 7;
  const int ln = (s >> 1) & 63;
  const int p  = s & 1;
  const int q  = qt * 64 + qw * 32 + (ln & 31);
  const int h  = ln >> 5;
  const int k0 = kb + 16 * p + 4 * h;
  float4 f0 = *(const float4*)(A + (size_t)q * kN + k0);
  float4 f1 = *(const float4*)(A + (size_t)q * kN + k0 + 8);
  i32x4 u;
  u[0] = (int)pkbf(f0.x, f0.y); u[1] = (int)pkbf(f0.z, f0.w);
  u[2] = (int)pkbf(f1.x, f1.y); u[3] = (int)pkbf(f1.z, f1.w);
  *(i32x4*)(dst + (size_t)qw * 1024 + ln * 16 + p * 8) = u;
}

// ---------------- main fused kernel ----------------
template<int AMODE>
__global__ __launch_bounds__(256)
void sdgcn_v18(const float* __restrict__ X, const float* __restrict__ A,
               const float* __restrict__ W, const float* __restrict__ gamma,
               const float* __restrict__ beta, float* __restrict__ out,
               const short* __restrict__ Xh, const short* __restrict__ XTh,
               const short* __restrict__ Af)
{
  // LDS 38912B: per wave 9728B { Kw[32*72] shorts ; Vw[64*40] shorts }.
  // post-loop union (after post-loop barrier): aM/aZ/aF @0, Har @1792.
  __shared__ __align__(16) unsigned char LB[38912];

  const int t    = threadIdx.x;
  const int wave = t >> 6;
  const int lane = t & 63;
  const int kg   = wave >> 1;      // k-group 0/1 (512 k each)
  const int qw   = wave & 1;       // q-wave 0/1 (32 rows each)
  const int half = lane >> 5;
  const int l31  = lane & 31;
  const int bid  = blockIdx.x;
  const int swz  = (bid & 7) * 96 + (bid >> 3);   // XCD-chunked (768 = 8*96)
  const int bt   = swz >> 4;
  const int qt   = swz & 15;
  const int qblk = qt * 64;
  const size_t xb = (size_t)bt * 65536;

  short* Kw  = (short*)(LB + wave * 9728);          // 32 x 72 shorts
  short* Vw  = (short*)(LB + wave * 9728 + 4608);   // 64 x 40 shorts
  float* aM  = (float*)LB;             // [2][64]
  float* aZ  = aM + 128;
  float* aF  = aZ + 128;               // [3][64]
  float* Har = (float*)(LB + 1792);    // [64][68]

  // ---- Q B-frags (RNE bf16, hi only)
  const int qmine = qblk + qw * 32 + l31;
  bf16x8 qh[4];
#pragma unroll
  for (int c = 0; c < 4; ++c)
    qh[c] = *(const bf16x8*)(Xh + xb + (size_t)qmine * kD + 16 * c + half * 8);

  f32x16 o0, o1;
#pragma unroll
  for (int r = 0; r < 16; ++r) { o0[r] = 0.f; o1[r] = 0.f; }
  float mrun = -INFINITY, Z = 0.f;

  // wave-private staging: lane covers 4 x 16B of each 4KB tile
  auto ldK8 = [&](int kb, bf16x8 r[4]) {
#pragma unroll
    for (int j = 0; j < 4; ++j) {
      int idx = lane + 64 * j;            // 0..255 chunks
      int kr = idx >> 3, kc = (idx & 7) * 8;
      r[j] = *(const bf16x8*)(Xh + xb + (size_t)(kb + kr) * kD + kc);
    }
  };
  auto stK8 = [&](const bf16x8 r[4]) {
#pragma unroll
    for (int j = 0; j < 4; ++j) {
      int idx = lane + 64 * j;
      *(bf16x8*)&Kw[(idx >> 3) * 72 + (idx & 7) * 8] = r[j];
    }
  };
  auto ldV8 = [&](int kb, bf16x8 r[4]) {
#pragma unroll
    for (int j = 0; j < 4; ++j) {
      int idx = lane + 64 * j;            // 0..255: 64 d-rows x 4 chunks
      int vd = idx >> 2, vm = (idx & 3) * 8;
      r[j] = *(const bf16x8*)(XTh + xb + (size_t)vd * 1024 + kb + vm);
    }
  };
  auto stV8 = [&](const bf16x8 r[4]) {
#pragma unroll
    for (int j = 0; j < 4; ++j) {
      int idx = lane + 64 * j;
      *(bf16x8*)&Vw[(idx >> 2) * 40 + (idx & 3) * 8] = r[j];
    }
  };

  i32x4 aA = {0,0,0,0}, aB = {0,0,0,0};

  // ---- prologue: stage tile 0 (wave-local; no barrier needed)
  {
    bf16x8 kr4[4], vr4[4];
    ldK8(kg * 512, kr4); ldV8(kg * 512, vr4);
    stK8(kr4); stV8(vr4);
  }
  if (AMODE == 1) {
    const short* Ab = Af + ((size_t)(qt * 32 + kg * 16) * 2048)
                         + (size_t)qw * 1024 + (lane << 4);
    aA = *(const i32x4*)(Ab);
    aB = *(const i32x4*)(Ab + 8);
  }

  for (int ts = 0; ts < 16; ++ts) {
    const int kb = kg * 512 + ts * 32;
    const bool pfm = (ts + 1) < 16;

    // T14: issue next tile's globals and next step's A early
    bf16x8 nk[4], nv[4];
    if (pfm) { ldK8(kb + 32, nk); ldV8(kb + 32, nv); }
    i32x4 naA = {0,0,0,0}, naB = {0,0,0,0};
    if (AMODE == 1 && pfm) {
      const short* Ab = Af + ((size_t)(qt * 32 + kg * 16 + ts + 1) * 2048)
                           + (size_t)qw * 1024 + (lane << 4);
      naA = *(const i32x4*)(Ab);
      naB = *(const i32x4*)(Ab + 8);
    }

    // A gate: agv[r] = A[qmine][kb + (r&3) + 8*(r>>2) + 4*half]
    float agv[16];
    if (AMODE == 1) {
      unsigned u[8] = {(unsigned)aA[0],(unsigned)aA[1],(unsigned)aA[2],(unsigned)aA[3],
                       (unsigned)aB[0],(unsigned)aB[1],(unsigned)aB[2],(unsigned)aB[3]};
#pragma unroll
      for (int m = 0; m < 8; ++m) {
        agv[2*m]   = __uint_as_float(u[m] << 16);
        agv[2*m+1] = __uint_as_float(u[m] & 0xFFFF0000u);
      }
    } else {
      const float* Arow = A + (size_t)qmine * kN + kb + 4 * half;
      float4 ag0 = *(const float4*)(Arow);
      float4 ag1 = *(const float4*)(Arow + 8);
      float4 ag2 = *(const float4*)(Arow + 16);
      float4 ag3 = *(const float4*)(Arow + 24);
#pragma unroll
      for (int e = 0; e < 4; ++e) {
        agv[e] = ag0[e]; agv[4+e] = ag1[e]; agv[8+e] = ag2[e]; agv[12+e] = ag3[e];
      }
    }

    // ---- QK^T swapped, 1-term: S = Kh.Qh (reads queue after last writes,
    //      in-order DS guarantees fresh data)
    f32x16 sa;
#pragma unroll
    for (int r = 0; r < 16; ++r) sa[r] = 0.f;
    __builtin_amdgcn_s_setprio(1);
#pragma unroll
    for (int c = 0; c < 4; ++c) {
      bf16x8 kh = *(const bf16x8*)&Kw[l31 * 72 + 16 * c + half * 8];
      sa = MFMA32(kh, qh[c], sa);
    }
    __builtin_amdgcn_s_setprio(0);

    // ---- defer-max online softmax (tree max; exp2/fma path)
    float a0 = fmaxf(fmaxf(sa[0],  sa[1]),  sa[2]);
    float a1 = fmaxf(fmaxf(sa[3],  sa[4]),  sa[5]);
    float a2 = fmaxf(fmaxf(sa[6],  sa[7]),  sa[8]);
    float a3 = fmaxf(fmaxf(sa[9],  sa[10]), sa[11]);
    float a4 = fmaxf(fmaxf(sa[12], sa[13]), sa[14]);
    float b0 = fmaxf(fmaxf(a0, a1), a2);
    float sm = fmaxf(fmaxf(b0, fmaxf(a3, a4)), sa[15]);
    sm = fmaxf(sm, __shfl_xor(sm, 32, 64));
    if (__any(sm > mrun + 8.f)) {
      const float nm = fmaxf(mrun, sm);
      const float f  = exp2f((mrun - nm) * kLog2e);   // 0 on first tile
      mrun = nm; Z *= f;
#pragma unroll
      for (int r = 0; r < 16; ++r) {
        const float fr = __shfl(f, (r & 3) + 8 * (r >> 2) + 4 * half, 64);
        o0[r] *= fr; o1[r] *= fr;
      }
    }
    const float mb2 = mrun * kLog2e;
    float pv[16];
#pragma unroll
    for (int r = 0; r < 16; ++r) pv[r] = exp2f(fmaf(sa[r], kLog2e, -mb2));
    float z0 = (pv[0] + pv[1]) + (pv[2] + pv[3]);
    float z1 = (pv[4] + pv[5]) + (pv[6] + pv[7]);
    float z2 = (pv[8] + pv[9]) + (pv[10] + pv[11]);
    float z3 = (pv[12] + pv[13]) + (pv[14] + pv[15]);
    float zt = (z0 + z1) + (z2 + z3);
    zt += __shfl_xor(zt, 32, 64);
    Z += zt;

    float pa[16];
#pragma unroll
    for (int r = 0; r < 16; ++r) pa[r] = pv[r] * agv[r];

    // ---- pack gated P + 4-shuffle cross-half exchange (v13-verified)
    unsigned du[8];
#pragma unroll
    for (int j = 0; j < 8; ++j) du[j] = pkbf(pa[2*j], pa[2*j+1]);
    const bool lo = (half == 0);
    unsigned snd0 = lo ? du[2] : du[0];
    unsigned snd1 = lo ? du[3] : du[1];
    unsigned snd2 = lo ? du[6] : du[4];
    unsigned snd3 = lo ? du[7] : du[5];
    unsigned r0 = (unsigned)__shfl_xor((int)snd0, 32, 64);
    unsigned r1 = (unsigned)__shfl_xor((int)snd1, 32, 64);
    unsigned r2 = (unsigned)__shfl_xor((int)snd2, 32, 64);
    unsigned r3 = (unsigned)__shfl_xor((int)snd3, 32, 64);
    i32x4 w0, w1;
    w0[0] = (int)(lo ? du[0] : r0);
    w0[1] = (int)(lo ? du[1] : r1);
    w0[2] = (int)(lo ? r0 : du[2]);
    w0[3] = (int)(lo ? r1 : du[3]);
    w1[0] = (int)(lo ? du[4] : r2);
    w1[1] = (int)(lo ? du[5] : r3);
    w1[2] = (int)(lo ? r2 : du[6]);
    w1[3] = (int)(lo ? r3 : du[7]);
    bf16x8 pf0 = *(bf16x8*)&w0;
    bf16x8 pf1 = *(bf16x8*)&w1;

    // ---- PV(ts): O[q][d] += P[q][k] V[k][d]
    {
      bf16x8 v0 = *(const bf16x8*)&Vw[l31 * 40 + half * 8];
      bf16x8 v1 = *(const bf16x8*)&Vw[l31 * 40 + 16 + half * 8];
      bf16x8 v2 = *(const bf16x8*)&Vw[(32 + l31) * 40 + half * 8];
      bf16x8 v3 = *(const bf16x8*)&Vw[(32 + l31) * 40 + 16 + half * 8];
      __builtin_amdgcn_s_setprio(1);
      o0 = MFMA32(pf0, v0, o0);
      o0 = MFMA32(pf1, v1, o0);
      o1 = MFMA32(pf0, v2, o1);
      o1 = MFMA32(pf1, v3, o1);
      __builtin_amdgcn_s_setprio(0);
    }

    // ---- stage tile ts+1 (single buffer; DS in-order: these writes are
    //      processed after the reads above, no sync needed)
    if (pfm) { stK8(nk); stV8(nv); }

    aA = naA; aB = naB;
  }
  __syncthreads();   // all waves' tile reads done before Har overlays LB

  // ================= split-K merge (v5-verified) =================
  if (lane < 32) {
    aM[kg * 64 + qw * 32 + l31] = mrun;
    aZ[kg * 64 + qw * 32 + l31] = Z;
  }
  if (kg == 1) {
#pragma unroll
    for (int r = 0; r < 16; ++r) {
      const int qq = qw * 32 + (r & 3) + 8 * (r >> 2) + 4 * half;
      Har[qq * 68 + l31]      = o0[r];
      Har[qq * 68 + l31 + 32] = o1[r];
    }
  }
  __syncthreads();
  if (kg == 1 && lane < 32) {
    const int q = qw * 32 + l31;
    const float ma = aM[q], mb = mrun;
    const float m  = fmaxf(ma, mb);
    const float fa = __expf(ma - m), fb = __expf(mb - m);
    const float Zs = aZ[q] * fa + Z * fb;
    aF[q]       = fa;
    aF[64 + q]  = fb;
    aF[128 + q] = 1.0f / (8.0f * Zs);   // sqrt(64)=8
  }
  __syncthreads();
  if (kg == 0) {
#pragma unroll
    for (int r = 0; r < 16; ++r) {
      const int qq = qw * 32 + (r & 3) + 8 * (r >> 2) + 4 * half;
      const float fa = aF[qq], fb = aF[64 + qq];
      Har[qq * 68 + l31]      = o0[r] * fa + Har[qq * 68 + l31]      * fb;
      Har[qq * 68 + l31 + 32] = o1[r] * fa + Har[qq * 68 + l31 + 32] * fb;
    }
  }
  __syncthreads();

  // ================= epilogue (v2-verified 16x16 path) =================
  const int g  = lane >> 4;
  const int ql = lane & 15;
  const int er = wave * 16;
  const float i8z = aF[128 + er + ql];

  bf16x8 hh[2], hl[2];
#pragma unroll
  for (int kk = 0; kk < 2; ++kk) {
    const float* hp = &Har[(er + ql) * 68 + kk * 32 + g * 8];
    float4 v0 = *(const float4*)hp;
    float4 v1 = *(const float4*)(hp + 4);
    float v[8] = {v0.x*i8z, v0.y*i8z, v0.z*i8z, v0.w*i8z,
                  v1.x*i8z, v1.y*i8z, v1.z*i8z, v1.w*i8z};
#pragma unroll
    for (int e = 0; e < 8; ++e) { short a, b; splitv(v[e], a, b); hh[kk][e] = a; hl[kk][e] = b; }
  }

  f32x4 lin[4];
#pragma unroll
  for (int c = 0; c < 4; ++c) {
    bf16x8 wh[2], wl[2];
#pragma unroll
    for (int kk = 0; kk < 2; ++kk) {
      const float* wp = W + (size_t)(c * 16 + ql) * kD + kk * 32 + g * 8;
      float4 v0 = *(const float4*)wp;
      float4 v1 = *(const float4*)(wp + 4);
      float v[8] = {v0.x, v0.y, v0.z, v0.w, v1.x, v1.y, v1.z, v1.w};
#pragma unroll
      for (int e = 0; e < 8; ++e) { short a, b; splitv(v[e], a, b); wh[kk][e] = a; wl[kk][e] = b; }
    }
    f32x4 acc = {0.f, 0.f, 0.f, 0.f};
    acc = MFMA16(hh[0], wh[0], acc);
    acc = MFMA16(hh[1], wh[1], acc);
    acc = MFMA16(hh[0], wl[0], acc);
    acc = MFMA16(hh[1], wl[1], acc);
    acc = MFMA16(hl[0], wh[0], acc);
    acc = MFMA16(hl[1], wh[1], acc);
    lin[c] = acc;
  }

  float rl[4][4];
#pragma unroll
  for (int c = 0; c < 4; ++c)
#pragma unroll
    for (int r = 0; r < 4; ++r) rl[c][r] = fmaxf(lin[c][r], 0.f);

  float mu[4], rstd[4];
#pragma unroll
  for (int r = 0; r < 4; ++r) {
    float s1 = rl[0][r] + rl[1][r] + rl[2][r] + rl[3][r];
    float s2 = rl[0][r]*rl[0][r] + rl[1][r]*rl[1][r] + rl[2][r]*rl[2][r] + rl[3][r]*rl[3][r];
#pragma unroll
    for (int off = 1; off < 16; off <<= 1) {
      s1 += __shfl_xor(s1, off, 64);
      s2 += __shfl_xor(s2, off, 64);
    }
    mu[r] = s1 * (1.f / 64.f);
    const float var = s2 * (1.f / 64.f) - mu[r] * mu[r];
    rstd[r] = rsqrtf(var + 1e-5f);
  }

#pragma unroll
  for (int c = 0; c < 4; ++c) {
    const float gm = gamma[c * 16 + ql];
    const float bb = beta[c * 16 + ql];
#pragma unroll
    for (int r = 0; r < 4; ++r) {
      const int qrow = qblk + er + 4 * g + r;
      const size_t off = ((size_t)bt * kN + qrow) * kD + c * 16 + ql;
      out[off] = (rl[c][r] - mu[r]) * rstd[r] * gm + bb + X[off];
    }
  }
}

extern "C" void kernel_launch(void* const* d_in, const int* in_sizes, int n_in,
                              void* d_out, int out_size, void* d_ws, size_t ws_size,
                              hipStream_t stream) {
  const float* X     = (const float*)d_in[0];
  const float* A     = (const float*)d_in[1];
  const float* W     = (const float*)d_in[2];
  const float* gamma = (const float*)d_in[3];
  const float* beta  = (const float*)d_in[4];
  float* out = (float*)d_out;

  short* Xh  = (short*)d_ws;
  short* XTh = Xh  + kPlane;
  short* Af  = XTh + kPlane;

  const size_t need = (2 * kPlane + kAfShorts) * sizeof(short);

  presplit<<<dim3(48 * 16), 256, 0, stream>>>(X, Xh, XTh);
  if (ws_size >= need) {
    prearr_Abf<<<dim3(16 * 32), 256, 0, stream>>>(A, Af);
    sdgcn_v18<1><<<dim3(48 * 16), 256, 0, stream>>>(X, A, W, gamma, beta, out,
                                                    Xh, XTh, Af);
  } else {
    sdgcn_v18<0><<<dim3(48 * 16), 256, 0, stream>>>(X, A, W, gamma, beta, out,
                                                    Xh, XTh, Af);
  }
}